// Round 3
// baseline (2418.430 us; speedup 1.0000x reference)
//
#include <hip/hip_runtime.h>
#include <math.h>

#define DEV __device__ __forceinline__

// Exact (numpy-matching) squared distance: rn each op, association ((x+y)+z),
// NO fma contraction — required so discrete decisions (FPS argmax, ball
// membership) match the reference bit-for-bit.
DEV float d2_exact(float ax, float ay, float az, float bx, float by, float bz) {
  float dx = __fsub_rn(ax, bx);
  float dy = __fsub_rn(ay, by);
  float dz = __fsub_rn(az, bz);
  return __fadd_rn(__fadd_rn(__fmul_rn(dx, dx), __fmul_rn(dy, dy)),
                   __fmul_rn(dz, dz));
}

DEV float uni(float f) {  // wave-uniform value -> SGPR
  return __int_as_float(__builtin_amdgcn_readfirstlane(__float_as_int(f)));
}

// Packed dual-fp32 ops (IEEE rn, identical rounding to scalar __fadd_rn etc).
DEV float2 pk_add(float2 a, float2 b) {
  float2 d;
  asm("v_pk_add_f32 %0, %1, %2" : "=v"(d) : "v"(a), "v"(b));
  return d;
}
DEV float2 pk_mul(float2 a, float2 b) {
  float2 d;
  asm("v_pk_mul_f32 %0, %1, %2" : "=v"(d) : "v"(a), "v"(b));
  return d;
}

// DPP-shifted copy of v with -inf identity for invalid/masked lanes.
template <int CTRL, int RM>
DEV float dppmax_mv(float v) {
  int s = __builtin_amdgcn_update_dpp((int)0xFF800000u, __float_as_int(v), CTRL,
                                      RM, 0xf, false);
  return __int_as_float(s);
}

// Cross-wave partial exchange slots (double-buffered -> 1 barrier per step).
struct FpsPart {
  float v[2][4];
  int idx[2][4];
  float x[2][4], y[2][4], z[2][4];
};

// ---------------------------------------------------------------------------
// Farthest point sampling core: 256 threads, one block per cloud, N=PPT*256.
// Per step: packed min-distance update + contiguous-block tournament argmax +
// DPP wave max + ballot first-index + pre-barrier winner-pos fetch + single
// barrier + 4-way partial combine. NO VMEM inside the loop (q buffered in
// LDS) so the per-step barrier never drains vmcnt.
// ---------------------------------------------------------------------------
template <int PPT>
DEV void fps_core(const float* __restrict__ p, int stride, int S,
                  float* __restrict__ qg, float* __restrict__ px,
                  float* __restrict__ py, float* __restrict__ pz,
                  float* __restrict__ qlds, FpsPart* part) {
  constexpr int N = PPT * 256;
  constexpr int NP = PPT / 2;
  const int tid = threadIdx.x;
  const int lane = tid & 63, wv = tid >> 6;

  for (int n = tid; n < N; n += 256) {
    px[n] = p[(size_t)n * stride + 0];
    py[n] = p[(size_t)n * stride + 1];
    pz[n] = p[(size_t)n * stride + 2];
  }
  __syncthreads();

  float2 mx2[NP], my2[NP], mz2[NP], md2[NP];
#pragma unroll
  for (int j = 0; j < NP; ++j) {
    int n = tid * PPT + 2 * j;  // contiguous ownership: lane order == index order
    mx2[j].x = px[n];
    mx2[j].y = px[n + 1];
    my2[j].x = py[n];
    my2[j].y = py[n + 1];
    mz2[j].x = pz[n];
    mz2[j].y = pz[n + 1];
    md2[j].x = INFINITY;
    md2[j].y = INFINITY;
  }

  float lx = uni(px[0]), ly = uni(py[0]), lz = uni(pz[0]);
  if (tid == 0) { qlds[0] = lx; qlds[1] = ly; qlds[2] = lz; }

  for (int s = 1; s < S; ++s) {
    // --- packed min-distance update (a - c computed as a + (-c): exact) ---
    float2 nlx, nly, nlz;
    nlx.x = nlx.y = -lx;
    nly.x = nly.y = -ly;
    nlz.x = nlz.y = -lz;
#pragma unroll
    for (int j = 0; j < NP; ++j) {
      float2 dx = pk_add(mx2[j], nlx);
      float2 dy = pk_add(my2[j], nly);
      float2 dz = pk_add(mz2[j], nlz);
      float2 ss = pk_add(pk_add(pk_mul(dx, dx), pk_mul(dy, dy)), pk_mul(dz, dz));
      md2[j].x = fminf(md2[j].x, ss.x);
      md2[j].y = fminf(md2[j].y, ss.y);
    }
    // --- local argmax: contiguous-block tournament (left block = smaller
    // indices; strict > means left wins ties -> exact first-index) ---
    float v[PPT];
    int ix[PPT];
#pragma unroll
    for (int j = 0; j < NP; ++j) {
      v[2 * j] = md2[j].x;
      v[2 * j + 1] = md2[j].y;
      ix[2 * j] = 2 * j;
      ix[2 * j + 1] = 2 * j + 1;
    }
#pragma unroll
    for (int w = 1; w < PPT; w <<= 1) {
#pragma unroll
      for (int k = 0; k < PPT; k += 2 * w) {
        if (v[k + w] > v[k]) { v[k] = v[k + w]; ix[k] = ix[k + w]; }
      }
    }
    float bv = v[0];
    int bi = tid * PPT + ix[0];

    // --- wave max value via DPP (result in lane 63) ---
    float m0 = bv;
    m0 = fmaxf(m0, dppmax_mv<0x111, 0xf>(m0));  // row_shr:1
    m0 = fmaxf(m0, dppmax_mv<0x112, 0xf>(m0));  // row_shr:2
    m0 = fmaxf(m0, dppmax_mv<0x114, 0xf>(m0));  // row_shr:4
    m0 = fmaxf(m0, dppmax_mv<0x118, 0xf>(m0));  // row_shr:8
    m0 = fmaxf(m0, dppmax_mv<0x142, 0xa>(m0));  // row_bcast:15 rows 1,3
    m0 = fmaxf(m0, dppmax_mv<0x143, 0xc>(m0));  // row_bcast:31 rows 2,3
    float vmax =
        __int_as_float(__builtin_amdgcn_readlane(__float_as_int(m0), 63));
    // first lane holding the max -> globally smallest index within the wave
    unsigned long long mk = __ballot(bv == vmax);
    int src = __ffsll(mk) - 1;
    int wi = __builtin_amdgcn_readlane(bi, src);

    // --- pre-barrier: fetch winner pos, publish (v, idx, pos) partial ---
    const int sb = s & 1;
    if (lane == 0) {
      part->v[sb][wv] = vmax;
      part->idx[sb][wv] = wi;
      part->x[sb][wv] = px[wi];
      part->y[sb][wv] = py[wi];
      part->z[sb][wv] = pz[wi];
    }
    __syncthreads();

    // --- all threads combine the 4 wave partials (broadcast LDS reads) ---
    float4 v4 = *(const float4*)&part->v[sb][0];
    int4 i4 = *(const int4*)&part->idx[sb][0];
    float4 x4 = *(const float4*)&part->x[sb][0];
    float4 y4 = *(const float4*)&part->y[sb][0];
    float4 z4 = *(const float4*)&part->z[sb][0];
    float vv = v4.x, X = x4.x, Y = y4.x, Z = z4.x;
    int bi2 = i4.x;
    if (v4.y > vv || (v4.y == vv && i4.y < bi2)) {
      vv = v4.y; bi2 = i4.y; X = x4.y; Y = y4.y; Z = z4.y;
    }
    if (v4.z > vv || (v4.z == vv && i4.z < bi2)) {
      vv = v4.z; bi2 = i4.z; X = x4.z; Y = y4.z; Z = z4.z;
    }
    if (v4.w > vv || (v4.w == vv && i4.w < bi2)) {
      vv = v4.w; bi2 = i4.w; X = x4.w; Y = y4.w; Z = z4.w;
    }
    lx = uni(X);
    ly = uni(Y);
    lz = uni(Z);
    // LDS q buffer (no VMEM in loop -> barrier never waits vmcnt)
    if (tid == 0) {
      qlds[s * 3 + 0] = lx;
      qlds[s * 3 + 1] = ly;
      qlds[s * 3 + 2] = lz;
    }
  }
  __syncthreads();
  for (int i = tid; i < S * 3; i += 256) qg[i] = qlds[i];
}

// ---------------------------------------------------------------------------
// FPS layer 1: x [4,4096,6] -> qpos1 [4,2048,3]. One block per batch.
// ---------------------------------------------------------------------------
__global__ __launch_bounds__(256) void fps1_kernel(const float* __restrict__ x,
                                                   float* __restrict__ qpos1) {
  __shared__ __align__(16) float smem[4096 * 3 + 2048 * 3 + 64];
  const float* p = x + (size_t)blockIdx.x * 4096 * 6;
  float* q = qpos1 + (size_t)blockIdx.x * 2048 * 3;
  fps_core<16>(p, 6, 2048, q, smem, smem + 4096, smem + 8192, smem + 12288,
               (FpsPart*)(smem + 12288 + 6144));
}

// ---------------------------------------------------------------------------
// Dense MLP layer, one neighbor per lane; weights via wave-uniform loads.
// w is [CIN, WSTRIDE] row-major, columns [0, COUT). relu fused.
// ---------------------------------------------------------------------------
template <int CIN, int COUT, int WSTRIDE>
DEV void mlp_layer(const float* __restrict__ hin, float* __restrict__ hout,
                   const float* __restrict__ w, const float* __restrict__ b) {
#pragma unroll
  for (int j = 0; j < COUT; j += 4) {
    float4 acc = *(const float4*)(b + j);
#pragma unroll
    for (int c = 0; c < CIN; ++c) {
      float4 wvec = *(const float4*)(w + (size_t)c * WSTRIDE + j);
      acc.x = fmaf(hin[c], wvec.x, acc.x);
      acc.y = fmaf(hin[c], wvec.y, acc.y);
      acc.z = fmaf(hin[c], wvec.z, acc.z);
      acc.w = fmaf(hin[c], wvec.w, acc.w);
    }
    hout[j + 0] = fmaxf(acc.x, 0.f);
    hout[j + 1] = fmaxf(acc.y, 0.f);
    hout[j + 2] = fmaxf(acc.z, 0.f);
    hout[j + 3] = fmaxf(acc.w, 0.f);
  }
}

// Folding max-pool across 64 lanes for 64 channels held per-lane in v[64].
// After the fold, lane l holds the cross-lane max of channel l in v[0].
DEV void pool64(float* v, int lane) {
#pragma unroll
  for (int o = 32; o >= 1; o >>= 1) {
    bool bit = (lane & o) != 0;
#pragma unroll
    for (int j = 0; j < o; ++j) {
      float send = bit ? v[j] : v[j + o];
      float keep = bit ? v[j + o] : v[j];
      float recv = __shfl_xor(send, o, 64);
      v[j] = fmaxf(keep, recv);
    }
  }
}

// Ordered ball query: first (up to) 64 lowest-index points with d2 <= r2.
DEV int ball_query_wave(const float* __restrict__ pos, int stride, int n_pts,
                        float qx, float qy, float qz, float r2, int lane,
                        int* __restrict__ nls, bool& valid) {
  int cnt = 0;
  for (int base = 0; base < n_pts && cnt < 64; base += 64) {
    int n = base + lane;
    float d2 = d2_exact(pos[(size_t)n * stride + 0], pos[(size_t)n * stride + 1],
                        pos[(size_t)n * stride + 2], qx, qy, qz);
    bool in = (d2 <= r2);
    unsigned long long m = __ballot(in);
    int slot = cnt + (int)__popcll(m & ((1ull << lane) - 1ull));
    if (in && slot < 64) nls[slot] = n;
    cnt += (int)__popcll(m);
  }
  int kcnt = cnt < 64 ? cnt : 64;
  valid = lane < kcnt;
  return valid ? nls[lane] : 0;
}

// ---------------------------------------------------------------------------
// Fused dispatch: blocks 0..3 = FPS layer 2 (qpos1 [4,2048,3] -> qpos2
// [4,512,3]); blocks 4..2051 = SetConv layer 1 (independent of fps2, both
// consume fps1 output). fps2 blocks first so they start immediately.
// ---------------------------------------------------------------------------
__global__ __launch_bounds__(256) void sc1_fps2_kernel(
    const float* __restrict__ x, const float* __restrict__ qpos1,
    const float* __restrict__ wa, const float* __restrict__ ba,
    const float* __restrict__ wb, const float* __restrict__ bb,
    const float* __restrict__ wc, const float* __restrict__ bc,
    float* __restrict__ feat1, float* __restrict__ qpos2) {
  __shared__ __align__(16) float smem[2048 * 3 + 512 * 3 + 64];

  if (blockIdx.x < 4) {
    const float* p = qpos1 + (size_t)blockIdx.x * 2048 * 3;
    float* q = qpos2 + (size_t)blockIdx.x * 512 * 3;
    fps_core<8>(p, 3, 512, q, smem, smem + 2048, smem + 4096, smem + 6144,
                (FpsPart*)(smem + 6144 + 1536));
    return;
  }

  // ---- setconv1: MLP 6->32->32->64, r^2=0.25, one wave per query ----
  int* nls = (int*)smem;  // [4][64]
  const int lane = threadIdx.x & 63, wv = threadIdx.x >> 6;
  const int qi = (blockIdx.x - 4) * 4 + wv;  // 0..8191
  const int b = qi >> 11;
  const float* xb = x + (size_t)b * 4096 * 6;
  const float qx = qpos1[qi * 3 + 0], qy = qpos1[qi * 3 + 1],
              qz = qpos1[qi * 3 + 2];

  bool valid;
  int nb =
      ball_query_wave(xb, 6, 4096, qx, qy, qz, 0.25f, lane, nls + wv * 64, valid);

  const float* xr = xb + (size_t)nb * 6;
  float h0[6];
  h0[0] = xr[3];
  h0[1] = xr[4];
  h0[2] = xr[5];
  h0[3] = xr[0] - qx;
  h0[4] = xr[1] - qy;
  h0[5] = xr[2] - qz;

  float h1[32];
  mlp_layer<6, 32, 32>(h0, h1, wa, ba);
  float h2[32];
  mlp_layer<32, 32, 32>(h1, h2, wb, bb);
  float h3[64];
  mlp_layer<32, 64, 64>(h2, h3, wc, bc);

  if (!valid) {
#pragma unroll
    for (int j = 0; j < 64; ++j) h3[j] = -INFINITY;
  }
  pool64(h3, lane);
  feat1[(size_t)qi * 64 + lane] = h3[0];  // lane l holds channel l
}

// ---------------------------------------------------------------------------
// SetConv layer 2: queries [4,512], points qpos1 [4,2048,3] + feat1
// [4,2048,64]. MLP 67->64->64->128, r^2=1.0. Also fills the batch output.
// ---------------------------------------------------------------------------
__global__ __launch_bounds__(256) void setconv2_kernel(
    const float* __restrict__ feat1, const float* __restrict__ qpos1,
    const float* __restrict__ qpos2, const float* __restrict__ wa,
    const float* __restrict__ ba, const float* __restrict__ wb,
    const float* __restrict__ bb, const float* __restrict__ wc,
    const float* __restrict__ bc, float* __restrict__ feat_out,
    float* __restrict__ batch) {
  __shared__ int nls[4][64];
  const int lane = threadIdx.x & 63, wv = threadIdx.x >> 6;
  const int qi = blockIdx.x * 4 + wv;  // 0..2047
  const int b = qi >> 9;
  const float* pb = qpos1 + (size_t)b * 2048 * 3;
  const float* fb = feat1 + (size_t)b * 2048 * 64;
  const float qx = qpos2[qi * 3 + 0], qy = qpos2[qi * 3 + 1],
              qz = qpos2[qi * 3 + 2];

  if (threadIdx.x < 4) {
    int j = blockIdx.x * 4 + threadIdx.x;
    batch[j] = (float)(j >> 9);  // repeat(arange(4), 512)
  }

  bool valid;
  int nb = ball_query_wave(pb, 3, 2048, qx, qy, qz, 1.0f, lane, nls[wv], valid);

  float h0[67];
  {
    const float* fr = fb + (size_t)nb * 64;
#pragma unroll
    for (int c = 0; c < 64; c += 4) {
      float4 v = *(const float4*)(fr + c);
      h0[c + 0] = v.x;
      h0[c + 1] = v.y;
      h0[c + 2] = v.z;
      h0[c + 3] = v.w;
    }
    const float* pr = pb + (size_t)nb * 3;
    h0[64] = pr[0] - qx;
    h0[65] = pr[1] - qy;
    h0[66] = pr[2] - qz;
  }

  float h1[64];
  mlp_layer<67, 64, 64>(h0, h1, wa, ba);
  float h2[64];
  mlp_layer<64, 64, 64>(h1, h2, wb, bb);

#pragma unroll 1
  for (int half = 0; half < 2; ++half) {
    float h3[64];
    mlp_layer<64, 64, 128>(h2, h3, wc + half * 64, bc + half * 64);
    if (!valid) {
#pragma unroll
      for (int j = 0; j < 64; ++j) h3[j] = -INFINITY;
    }
    pool64(h3, lane);
    feat_out[(size_t)qi * 128 + half * 64 + lane] = h3[0];
  }
}

// ---------------------------------------------------------------------------
extern "C" void kernel_launch(void* const* d_in, const int* in_sizes, int n_in,
                              void* d_out, int out_size, void* d_ws,
                              size_t ws_size, hipStream_t stream) {
  const float* x   = (const float*)d_in[0];
  const float* w1a = (const float*)d_in[1];
  const float* b1a = (const float*)d_in[2];
  const float* w1b = (const float*)d_in[3];
  const float* b1b = (const float*)d_in[4];
  const float* w1c = (const float*)d_in[5];
  const float* b1c = (const float*)d_in[6];
  const float* w2a = (const float*)d_in[7];
  const float* b2a = (const float*)d_in[8];
  const float* w2b = (const float*)d_in[9];
  const float* b2b = (const float*)d_in[10];
  const float* w2c = (const float*)d_in[11];
  const float* b2c = (const float*)d_in[12];

  float* out = (float*)d_out;
  float* qpos1 = (float*)d_ws;                  // 4*2048*3 floats
  float* feat1 = qpos1 + 4 * 2048 * 3;          // 4*2048*64 floats
  float* feat2 = out;                           // 2048*128
  float* qpos2 = out + 2048 * 128;              // 2048*3
  float* batch = out + 2048 * 128 + 2048 * 3;   // 2048

  fps1_kernel<<<4, 256, 0, stream>>>(x, qpos1);
  sc1_fps2_kernel<<<2052, 256, 0, stream>>>(x, qpos1, w1a, b1a, w1b, b1b, w1c,
                                            b1c, feat1, qpos2);
  setconv2_kernel<<<512, 256, 0, stream>>>(feat1, qpos1, qpos2, w2a, b2a, w2b,
                                           b2b, w2c, b2c, feat2, batch);
}

// Round 4
// 1815.249 us; speedup vs baseline: 1.3323x; 1.3323x over previous
//
#include <hip/hip_runtime.h>
#include <math.h>

#define DEV __device__ __forceinline__

// Exact (numpy-matching) squared distance: rn each op, association ((x+y)+z),
// NO fma contraction — required so discrete decisions (FPS argmax, ball
// membership) match the reference bit-for-bit.
DEV float d2_exact(float ax, float ay, float az, float bx, float by, float bz) {
  float dx = __fsub_rn(ax, bx);
  float dy = __fsub_rn(ay, by);
  float dz = __fsub_rn(az, bz);
  return __fadd_rn(__fadd_rn(__fmul_rn(dx, dx), __fmul_rn(dy, dy)),
                   __fmul_rn(dz, dz));
}

DEV float uni(float f) {  // wave-uniform value -> SGPR
  return __int_as_float(__builtin_amdgcn_readfirstlane(__float_as_int(f)));
}

// Packed dual-fp32 ops (IEEE rn, identical rounding to scalar __fadd_rn etc).
DEV float2 pk_add(float2 a, float2 b) {
  float2 d;
  asm("v_pk_add_f32 %0, %1, %2" : "=v"(d) : "v"(a), "v"(b));
  return d;
}
DEV float2 pk_mul(float2 a, float2 b) {
  float2 d;
  asm("v_pk_mul_f32 %0, %1, %2" : "=v"(d) : "v"(a), "v"(b));
  return d;
}

// DPP-shifted copy of v with -inf identity for invalid/masked lanes.
template <int CTRL, int RM>
DEV float dppmax_mv(float v) {
  int s = __builtin_amdgcn_update_dpp((int)0xFF800000u, __float_as_int(v), CTRL,
                                      RM, 0xf, false);
  return __int_as_float(s);
}

DEV unsigned long long u64max(unsigned long long a, unsigned long long b) {
  return a > b ? a : b;
}

// Cross-wave partial exchange: one u64 key per wave, double-buffered so a
// single barrier per step suffices. key = (d2_bits << 32) | ~idx — d2 >= 0 so
// float bits are order-monotonic; ~idx makes u64-max prefer the SMALLEST
// index on value ties (exact jnp.argmax first-index semantics).
struct __align__(16) FpsPart {
  unsigned long long key[2][4];
};

// ---------------------------------------------------------------------------
// Farthest point sampling core: 256 threads, one block per cloud, N=PPT*256.
// Per step: packed min-dist update with fused first-index argmax + DPP wave
// value-max + ballot first-lane + u64-key exchange (1 ds_write_b64 per wave)
// + single barrier + 3 u64-max combine + broadcast pos fetch.
// ---------------------------------------------------------------------------
template <int PPT>
DEV void fps_core(const float* __restrict__ p, int stride, int S,
                  float* __restrict__ q, float* __restrict__ px,
                  float* __restrict__ py, float* __restrict__ pz,
                  FpsPart* part) {
  constexpr int N = PPT * 256;
  constexpr int NP = PPT / 2;
  const int tid = threadIdx.x;
  const int lane = tid & 63, wv = tid >> 6;
  const int base = tid * PPT;

  for (int n = tid; n < N; n += 256) {
    px[n] = p[(size_t)n * stride + 0];
    py[n] = p[(size_t)n * stride + 1];
    pz[n] = p[(size_t)n * stride + 2];
  }
  __syncthreads();

  float2 mx2[NP], my2[NP], mz2[NP], md2[NP];
#pragma unroll
  for (int j = 0; j < NP; ++j) {
    int n = base + 2 * j;  // contiguous ownership: lane order == index order
    mx2[j].x = px[n];
    mx2[j].y = px[n + 1];
    my2[j].x = py[n];
    my2[j].y = py[n + 1];
    mz2[j].x = pz[n];
    mz2[j].y = pz[n + 1];
    md2[j].x = INFINITY;
    md2[j].y = INFINITY;
  }

  float lx = uni(px[0]), ly = uni(py[0]), lz = uni(pz[0]);
  if (tid == 0) { q[0] = lx; q[1] = ly; q[2] = lz; }

  for (int s = 1; s < S; ++s) {
    // --- packed min-dist update + fused first-index argmax (strict >) ---
    float2 nl_x, nl_y, nl_z;  // hoisted negated center (a + (-c) == a - c)
    nl_x.x = nl_x.y = -lx;
    nl_y.x = nl_y.y = -ly;
    nl_z.x = nl_z.y = -lz;
    float bv = -INFINITY;
    int bk = 0;  // local point index 0..PPT-1 (inline-const candidates)
#pragma unroll
    for (int j = 0; j < NP; ++j) {
      float2 dx = pk_add(mx2[j], nl_x);
      float2 dy = pk_add(my2[j], nl_y);
      float2 dz = pk_add(mz2[j], nl_z);
      float2 ss = pk_add(pk_add(pk_mul(dx, dx), pk_mul(dy, dy)), pk_mul(dz, dz));
      float m0 = fminf(md2[j].x, ss.x);
      float m1 = fminf(md2[j].y, ss.y);
      md2[j].x = m0;
      md2[j].y = m1;
      if (m0 > bv) { bv = m0; bk = 2 * j; }
      if (m1 > bv) { bv = m1; bk = 2 * j + 1; }
    }
    int bi = base + bk;

    // --- wave value-max via DPP (result in lane 63) ---
    float m0 = bv;
    m0 = fmaxf(m0, dppmax_mv<0x111, 0xf>(m0));  // row_shr:1
    m0 = fmaxf(m0, dppmax_mv<0x112, 0xf>(m0));  // row_shr:2
    m0 = fmaxf(m0, dppmax_mv<0x114, 0xf>(m0));  // row_shr:4
    m0 = fmaxf(m0, dppmax_mv<0x118, 0xf>(m0));  // row_shr:8
    m0 = fmaxf(m0, dppmax_mv<0x142, 0xa>(m0));  // row_bcast:15 rows 1,3
    m0 = fmaxf(m0, dppmax_mv<0x143, 0xc>(m0));  // row_bcast:31 rows 2,3
    float vmax =
        __int_as_float(__builtin_amdgcn_readlane(__float_as_int(m0), 63));
    // first lane holding the max -> smallest owned index within the wave
    unsigned long long mk = __ballot(bv == vmax);
    int src = __ffsll(mk) - 1;
    int wi = __builtin_amdgcn_readlane(bi, src);

    // --- publish wave key, barrier, combine 4 keys, fetch winner pos ---
    const int sb = s & 1;
    if (lane == 0) {
      part->key[sb][wv] =
          ((unsigned long long)(unsigned int)__float_as_int(vmax) << 32) |
          (unsigned int)~wi;
    }
    __syncthreads();

    ulonglong2 k01 = *(const ulonglong2*)&part->key[sb][0];
    ulonglong2 k23 = *(const ulonglong2*)&part->key[sb][2];
    unsigned long long kb = u64max(u64max(k01.x, k01.y), u64max(k23.x, k23.y));
    int i0 = (int)~(unsigned int)kb;

    lx = uni(px[i0]);  // same address all lanes -> LDS broadcast
    ly = uni(py[i0]);
    lz = uni(pz[i0]);
    // global q store: retires during the next step, off the critical path
    if (tid == 0) { q[s * 3 + 0] = lx; q[s * 3 + 1] = ly; q[s * 3 + 2] = lz; }
  }
}

// ---------------------------------------------------------------------------
// FPS layer 1: x [4,4096,6] -> qpos1 [4,2048,3]. One block per batch.
// ---------------------------------------------------------------------------
__global__ __launch_bounds__(256) void fps1_kernel(const float* __restrict__ x,
                                                   float* __restrict__ qpos1) {
  __shared__ __align__(16) float smem[4096 * 3 + 16];
  const float* p = x + (size_t)blockIdx.x * 4096 * 6;
  float* q = qpos1 + (size_t)blockIdx.x * 2048 * 3;
  fps_core<16>(p, 6, 2048, q, smem, smem + 4096, smem + 8192,
               (FpsPart*)(smem + 12288));
}

// ---------------------------------------------------------------------------
// Dense MLP layer, one neighbor per lane; weights via wave-uniform loads.
// w is [CIN, WSTRIDE] row-major, columns [0, COUT). relu fused.
// ---------------------------------------------------------------------------
template <int CIN, int COUT, int WSTRIDE>
DEV void mlp_layer(const float* __restrict__ hin, float* __restrict__ hout,
                   const float* __restrict__ w, const float* __restrict__ b) {
#pragma unroll
  for (int j = 0; j < COUT; j += 4) {
    float4 acc = *(const float4*)(b + j);
#pragma unroll
    for (int c = 0; c < CIN; ++c) {
      float4 wvec = *(const float4*)(w + (size_t)c * WSTRIDE + j);
      acc.x = fmaf(hin[c], wvec.x, acc.x);
      acc.y = fmaf(hin[c], wvec.y, acc.y);
      acc.z = fmaf(hin[c], wvec.z, acc.z);
      acc.w = fmaf(hin[c], wvec.w, acc.w);
    }
    hout[j + 0] = fmaxf(acc.x, 0.f);
    hout[j + 1] = fmaxf(acc.y, 0.f);
    hout[j + 2] = fmaxf(acc.z, 0.f);
    hout[j + 3] = fmaxf(acc.w, 0.f);
  }
}

// Folding max-pool across 64 lanes for 64 channels held per-lane in v[64].
// After the fold, lane l holds the cross-lane max of channel l in v[0].
DEV void pool64(float* v, int lane) {
#pragma unroll
  for (int o = 32; o >= 1; o >>= 1) {
    bool bit = (lane & o) != 0;
#pragma unroll
    for (int j = 0; j < o; ++j) {
      float send = bit ? v[j] : v[j + o];
      float keep = bit ? v[j + o] : v[j];
      float recv = __shfl_xor(send, o, 64);
      v[j] = fmaxf(keep, recv);
    }
  }
}

// Ordered ball query: first (up to) 64 lowest-index points with d2 <= r2.
DEV int ball_query_wave(const float* __restrict__ pos, int stride, int n_pts,
                        float qx, float qy, float qz, float r2, int lane,
                        int* __restrict__ nls, bool& valid) {
  int cnt = 0;
  for (int base = 0; base < n_pts && cnt < 64; base += 64) {
    int n = base + lane;
    float d2 = d2_exact(pos[(size_t)n * stride + 0], pos[(size_t)n * stride + 1],
                        pos[(size_t)n * stride + 2], qx, qy, qz);
    bool in = (d2 <= r2);
    unsigned long long m = __ballot(in);
    int slot = cnt + (int)__popcll(m & ((1ull << lane) - 1ull));
    if (in && slot < 64) nls[slot] = n;
    cnt += (int)__popcll(m);
  }
  int kcnt = cnt < 64 ? cnt : 64;
  valid = lane < kcnt;
  return valid ? nls[lane] : 0;
}

// ---------------------------------------------------------------------------
// Fused dispatch: blocks 0..3 = FPS layer 2 (qpos1 [4,2048,3] -> qpos2
// [4,512,3]); blocks 4..2051 = SetConv layer 1 (independent of fps2, both
// consume fps1 output). fps2 blocks first so they start immediately.
// ---------------------------------------------------------------------------
__global__ __launch_bounds__(256) void sc1_fps2_kernel(
    const float* __restrict__ x, const float* __restrict__ qpos1,
    const float* __restrict__ wa, const float* __restrict__ ba,
    const float* __restrict__ wb, const float* __restrict__ bb,
    const float* __restrict__ wc, const float* __restrict__ bc,
    float* __restrict__ feat1, float* __restrict__ qpos2) {
  __shared__ __align__(16) float smem[2048 * 3 + 16];

  if (blockIdx.x < 4) {
    const float* p = qpos1 + (size_t)blockIdx.x * 2048 * 3;
    float* q = qpos2 + (size_t)blockIdx.x * 512 * 3;
    fps_core<8>(p, 3, 512, q, smem, smem + 2048, smem + 4096,
                (FpsPart*)(smem + 6144));
    return;
  }

  // ---- setconv1: MLP 6->32->32->64, r^2=0.25, one wave per query ----
  int* nls = (int*)smem;  // [4][64]
  const int lane = threadIdx.x & 63, wv = threadIdx.x >> 6;
  const int qi = (blockIdx.x - 4) * 4 + wv;  // 0..8191
  const int b = qi >> 11;
  const float* xb = x + (size_t)b * 4096 * 6;
  const float qx = qpos1[qi * 3 + 0], qy = qpos1[qi * 3 + 1],
              qz = qpos1[qi * 3 + 2];

  bool valid;
  int nb =
      ball_query_wave(xb, 6, 4096, qx, qy, qz, 0.25f, lane, nls + wv * 64, valid);

  const float* xr = xb + (size_t)nb * 6;
  float h0[6];
  h0[0] = xr[3];
  h0[1] = xr[4];
  h0[2] = xr[5];
  h0[3] = xr[0] - qx;
  h0[4] = xr[1] - qy;
  h0[5] = xr[2] - qz;

  float h1[32];
  mlp_layer<6, 32, 32>(h0, h1, wa, ba);
  float h2[32];
  mlp_layer<32, 32, 32>(h1, h2, wb, bb);
  float h3[64];
  mlp_layer<32, 64, 64>(h2, h3, wc, bc);

  if (!valid) {
#pragma unroll
    for (int j = 0; j < 64; ++j) h3[j] = -INFINITY;
  }
  pool64(h3, lane);
  feat1[(size_t)qi * 64 + lane] = h3[0];  // lane l holds channel l
}

// ---------------------------------------------------------------------------
// SetConv layer 2: queries [4,512], points qpos1 [4,2048,3] + feat1
// [4,2048,64]. MLP 67->64->64->128, r^2=1.0. Also fills the batch output.
// ---------------------------------------------------------------------------
__global__ __launch_bounds__(256) void setconv2_kernel(
    const float* __restrict__ feat1, const float* __restrict__ qpos1,
    const float* __restrict__ qpos2, const float* __restrict__ wa,
    const float* __restrict__ ba, const float* __restrict__ wb,
    const float* __restrict__ bb, const float* __restrict__ wc,
    const float* __restrict__ bc, float* __restrict__ feat_out,
    float* __restrict__ batch) {
  __shared__ int nls[4][64];
  const int lane = threadIdx.x & 63, wv = threadIdx.x >> 6;
  const int qi = blockIdx.x * 4 + wv;  // 0..2047
  const int b = qi >> 9;
  const float* pb = qpos1 + (size_t)b * 2048 * 3;
  const float* fb = feat1 + (size_t)b * 2048 * 64;
  const float qx = qpos2[qi * 3 + 0], qy = qpos2[qi * 3 + 1],
              qz = qpos2[qi * 3 + 2];

  if (threadIdx.x < 4) {
    int j = blockIdx.x * 4 + threadIdx.x;
    batch[j] = (float)(j >> 9);  // repeat(arange(4), 512)
  }

  bool valid;
  int nb = ball_query_wave(pb, 3, 2048, qx, qy, qz, 1.0f, lane, nls[wv], valid);

  float h0[67];
  {
    const float* fr = fb + (size_t)nb * 64;
#pragma unroll
    for (int c = 0; c < 64; c += 4) {
      float4 v = *(const float4*)(fr + c);
      h0[c + 0] = v.x;
      h0[c + 1] = v.y;
      h0[c + 2] = v.z;
      h0[c + 3] = v.w;
    }
    const float* pr = pb + (size_t)nb * 3;
    h0[64] = pr[0] - qx;
    h0[65] = pr[1] - qy;
    h0[66] = pr[2] - qz;
  }

  float h1[64];
  mlp_layer<67, 64, 64>(h0, h1, wa, ba);
  float h2[64];
  mlp_layer<64, 64, 64>(h1, h2, wb, bb);

#pragma unroll 1
  for (int half = 0; half < 2; ++half) {
    float h3[64];
    mlp_layer<64, 64, 128>(h2, h3, wc + half * 64, bc + half * 64);
    if (!valid) {
#pragma unroll
      for (int j = 0; j < 64; ++j) h3[j] = -INFINITY;
    }
    pool64(h3, lane);
    feat_out[(size_t)qi * 128 + half * 64 + lane] = h3[0];
  }
}

// ---------------------------------------------------------------------------
extern "C" void kernel_launch(void* const* d_in, const int* in_sizes, int n_in,
                              void* d_out, int out_size, void* d_ws,
                              size_t ws_size, hipStream_t stream) {
  const float* x   = (const float*)d_in[0];
  const float* w1a = (const float*)d_in[1];
  const float* b1a = (const float*)d_in[2];
  const float* w1b = (const float*)d_in[3];
  const float* b1b = (const float*)d_in[4];
  const float* w1c = (const float*)d_in[5];
  const float* b1c = (const float*)d_in[6];
  const float* w2a = (const float*)d_in[7];
  const float* b2a = (const float*)d_in[8];
  const float* w2b = (const float*)d_in[9];
  const float* b2b = (const float*)d_in[10];
  const float* w2c = (const float*)d_in[11];
  const float* b2c = (const float*)d_in[12];

  float* out = (float*)d_out;
  float* qpos1 = (float*)d_ws;                  // 4*2048*3 floats
  float* feat1 = qpos1 + 4 * 2048 * 3;          // 4*2048*64 floats
  float* feat2 = out;                           // 2048*128
  float* qpos2 = out + 2048 * 128;              // 2048*3
  float* batch = out + 2048 * 128 + 2048 * 3;   // 2048

  fps1_kernel<<<4, 256, 0, stream>>>(x, qpos1);
  sc1_fps2_kernel<<<2052, 256, 0, stream>>>(x, qpos1, w1a, b1a, w1b, b1b, w1c,
                                            b1c, feat1, qpos2);
  setconv2_kernel<<<512, 256, 0, stream>>>(feat1, qpos1, qpos2, w2a, b2a, w2b,
                                           b2b, w2c, b2c, feat2, batch);
}